// Round 8
// baseline (296.786 us; speedup 1.0000x reference)
//
#include <hip/hip_runtime.h>

#define NB 64
#define NPRED 25200
#define NCAND 2048
#define NSEL 1024
#define NDET 300
#define NBINS 8192
#define CONF_T 0.25f
#define IOU_T 0.45f
#define BASE_BITS 0x3E800000u   // bits of 0.25f

__device__ __forceinline__ float sigmoidf_(float x) {
    return 1.0f / (1.0f + expf(-x));
}

// LDS slot swizzle: +1 float4 pad every 8 slots (conflict-free 80B-stride reads).
#define SLOT(x) ((x) + ((x) >> 3))

// Bitonic compare-exchange via wave shuffle (partner distance j <= 32 stays
// inside a wave64). Bit-identical to the LDS pass: element e keeps
// (lower==up) ? max : min, up = ((e&k)==0), lower = ((e&j)==0).
__device__ __forceinline__ unsigned long long cex_(unsigned long long x,
                                                   int e, int k, int j) {
    unsigned long long y = __shfl_xor(x, j, 64);
    bool up = ((e & k) == 0);
    bool lower = ((e & j) == 0);
    unsigned long long mn = (x < y) ? x : y;
    unsigned long long mx = (x < y) ? y : x;
    return (lower == up) ? mx : mn;
}

// ---------------------------------------------------------------- scores
__global__ __launch_bounds__(256) void k_score(const float* __restrict__ r0,
                                               const float* __restrict__ r1,
                                               const float* __restrict__ r2,
                                               float* __restrict__ scores) {
    __shared__ float4 sm[SLOT(1280)];   // 1440 slots = 23 KB
    int b = blockIdx.x;
    int t = threadIdx.x;
    const float* src;
    int rec, img, n;
    if (b < 4800) {
        src = r0; rec = b * 256 + t;
        img = rec / 19200; n = rec - img * 19200;
    } else if (b < 6000) {
        src = r1; rec = (b - 4800) * 256 + t;
        img = rec / 4800;  n = 19200 + rec - img * 4800;
    } else {
        src = r2; rec = (b - 6000) * 256 + t;
        img = rec / 1200;  n = 24000 + rec - img * 1200;
    }
    const float4* g = (const float4*)src + (long)(rec - t) * 5;  // block base
#pragma unroll
    for (int k = 0; k < 5; ++k) {
        int x = t + 256 * k;
        sm[SLOT(x)] = g[x];
    }
    __syncthreads();
    float4 v0 = sm[SLOT(5 * t + 1)];
    float4 v1 = sm[SLOT(5 * t + 2)];
    float4 v2 = sm[SLOT(5 * t + 3)];
    float4 v3 = sm[SLOT(5 * t + 4)];
    float obj = sigmoidf_(v0.x);
    float m = v0.y;
    m = fmaxf(m, v0.z); m = fmaxf(m, v0.w);
    m = fmaxf(m, v1.x); m = fmaxf(m, v1.y); m = fmaxf(m, v1.z); m = fmaxf(m, v1.w);
    m = fmaxf(m, v2.x); m = fmaxf(m, v2.y); m = fmaxf(m, v2.z); m = fmaxf(m, v2.w);
    m = fmaxf(m, v3.x); m = fmaxf(m, v3.y); m = fmaxf(m, v3.z); m = fmaxf(m, v3.w);
    float best = obj * sigmoidf_(m);
    float sc = (obj > CONF_T && best > CONF_T) ? best : 0.0f;
    scores[(long)img * NPRED + n] = sc;
}

// ---------------------------------------------------------------- top-k + decode (fused)
__global__ __launch_bounds__(1024) void k_topk(const float* __restrict__ scores,
                                               const float* __restrict__ r0,
                                               const float* __restrict__ r1,
                                               const float* __restrict__ r2,
                                               const float* __restrict__ strd,
                                               const float* __restrict__ ag,
                                               float* __restrict__ sel_score,
                                               float* __restrict__ sel_box,
                                               float* __restrict__ sel_cls) {
    __shared__ unsigned int hist[NBINS];
    __shared__ unsigned int bufA[1024];
    __shared__ unsigned int bufB[1024];
    __shared__ unsigned long long sbuf[NCAND];
    __shared__ unsigned int s_thr;
    __shared__ unsigned int s_cnt;
    int img = blockIdx.x;
    int t = threadIdx.x;
    for (int b = t; b < NBINS; b += 1024) hist[b] = 0;
    if (t == 0) { s_thr = 0; s_cnt = 0; }
    __syncthreads();
    const float* sc = scores + (long)img * NPRED;
    float v[25];
#pragma unroll
    for (int i = 0; i < 25; ++i) {
        int n = t + i * 1024;
        v[i] = (n < NPRED) ? sc[n] : 0.0f;
        if (v[i] > CONF_T) {
            unsigned bin = (__float_as_uint(v[i]) - BASE_BITS) >> 11;
            if (bin > NBINS - 1u) bin = NBINS - 1u;
            atomicAdd(&hist[bin], 1u);
        }
    }
    __syncthreads();
    unsigned h[8];
    unsigned cs = 0;
    for (int b = 0; b < 8; ++b) { h[b] = hist[t * 8 + b]; cs += h[b]; }
    bufA[t] = cs;
    __syncthreads();
    unsigned int* srcp = bufA;
    unsigned int* dstp = bufB;
    for (int ofs = 1; ofs < 1024; ofs <<= 1) {
        unsigned vv = srcp[t];
        if (t >= ofs) vv += srcp[t - ofs];
        dstp[t] = vv;
        __syncthreads();
        unsigned int* tmp = srcp; srcp = dstp; dstp = tmp;
    }
    unsigned total = srcp[1023];
    unsigned above = total - srcp[t];
    if (total >= NSEL) {
        unsigned c = above;
        for (int b = 7; b >= 0; --b) {
            unsigned ci = c + h[b];
            if (c < NSEL && ci >= NSEL) {
                s_thr = BASE_BITS + ((unsigned)(t * 8 + b) << 11);
            }
            c = ci;
        }
    }
    __syncthreads();
    unsigned thr = s_thr;
#pragma unroll
    for (int i = 0; i < 25; ++i) {
        int n = t + i * 1024;
        if (v[i] > CONF_T) {
            unsigned bits = __float_as_uint(v[i]);
            if (bits >= thr) {
                unsigned pos = atomicAdd(&s_cnt, 1u);
                if (pos < NCAND)
                    sbuf[pos] = ((unsigned long long)bits << 32) |
                                (unsigned long long)(0xFFFFFFFFu - (unsigned)n);
            }
        }
    }
    __syncthreads();
    for (unsigned pos = s_cnt + (unsigned)t; pos < NCAND; pos += 1024) sbuf[pos] = 0ull;
    __syncthreads();

    // ---- hybrid bitonic sort: j<=32 passes in-register via shfl_xor ----
    {
        unsigned long long a = sbuf[t];
        unsigned long long b = sbuf[t + 1024];
#pragma unroll
        for (int k = 2; k <= 64; k <<= 1) {
#pragma unroll
            for (int j = k >> 1; j >= 1; j >>= 1) {
                a = cex_(a, t, k, j);
                b = cex_(b, t + 1024, k, j);
            }
        }
        sbuf[t] = a; sbuf[t + 1024] = b;
    }
    __syncthreads();
    for (int k = 128; k <= NCAND; k <<= 1) {
        for (int j = k >> 1; j >= 64; j >>= 1) {
            for (int e = t; e < NCAND; e += 1024) {
                int p = e ^ j;
                if (p > e) {
                    unsigned long long a = sbuf[e], b = sbuf[p];
                    bool up = ((e & k) == 0);
                    if ((a < b) == up) { sbuf[e] = b; sbuf[p] = a; }
                }
            }
            __syncthreads();
        }
        unsigned long long a = sbuf[t];
        unsigned long long b = sbuf[t + 1024];
#pragma unroll
        for (int j = 32; j >= 1; j >>= 1) {
            a = cex_(a, t, k, j);
            b = cex_(b, t + 1024, k, j);
        }
        sbuf[t] = a; sbuf[t + 1024] = b;
        __syncthreads();
    }

    unsigned long long key = sbuf[t];
    float scv = __uint_as_float((unsigned)(key >> 32));
    int idx = (int)(0xFFFFFFFFu - (unsigned)(key & 0xFFFFFFFFull));
    sel_score[img * NSEL + t] = scv;

    // ---- fused decode of the selected prediction ----
    float4 bb = make_float4(0.f, 0.f, 0.f, 0.f);
    float cls = 0.0f;
    if (scv > CONF_T) {
        int n = idx;
        const float* src;
        int a, y, x, cells, sidx, nxl;
        if (n < 19200) {
            sidx = 0; src = r0; cells = 6400; nxl = 80;
            int l = n;            a = l / 6400; int r = l - a * 6400; y = r / 80; x = r - y * 80;
        } else if (n < 24000) {
            sidx = 1; src = r1; cells = 1600; nxl = 40;
            int l = n - 19200;    a = l / 1600; int r = l - a * 1600; y = r / 40; x = r - y * 40;
        } else {
            sidx = 2; src = r2; cells = 400; nxl = 20;
            int l = n - 24000;    a = l / 400;  int r = l - a * 400;  y = r / 20; x = r - y * 20;
        }
        long base = (((long)img * 3 + a) * cells + (long)y * nxl + x) * 20;
        const float4* p = (const float4*)(src + base);
        float4 v0 = p[0];
        float st = strd[sidx];
        float aw = ag[(sidx * 3 + a) * 2 + 0];
        float ah = ag[(sidx * 3 + a) * 2 + 1];
        float cx = (sigmoidf_(v0.x) * 2.0f - 0.5f + (float)x) * st;
        float cy = (sigmoidf_(v0.y) * 2.0f - 0.5f + (float)y) * st;
        float tw = sigmoidf_(v0.z) * 2.0f;
        float th = sigmoidf_(v0.w) * 2.0f;
        float w = tw * tw * aw;
        float hh = th * th * ah;
        bb.x = cx - w * 0.5f;
        bb.y = cy - hh * 0.5f;
        bb.z = cx + w * 0.5f;
        bb.w = cy + hh * 0.5f;
        float4 c0 = p[1], c1 = p[2], c2 = p[3], c3 = p[4];
        float vals[15] = { c0.y, c0.z, c0.w,
                           c1.x, c1.y, c1.z, c1.w,
                           c2.x, c2.y, c2.z, c2.w,
                           c3.x, c3.y, c3.z, c3.w };
        float bv = vals[0]; int bi = 0;
#pragma unroll
        for (int k = 1; k < 15; ++k) if (vals[k] > bv) { bv = vals[k]; bi = k; }
        cls = (float)bi;
    }
    ((float4*)sel_box)[img * NSEL + t] = bb;
    sel_cls[img * NSEL + t] = cls;
}

// ---------------------------------------------------------------- IoU mask (fat blocks, wave jobs)
// maskT[img][jt][i]: bit b set <=> j=jt*64+b > i and IoU > 0.45.
// 256 blocks x 16 waves; each wave grid-strides over the 8704 (img, it<=jt)
// tile jobs (1 block/CU, 4 waves/SIMD -- no tiny-block launch overhead).
// Lane owns row i = it*64+lane (coalesced vector load); (img,it,jt) forced
// wave-uniform via readfirstlane so j-tile loads take the SCALAR path (SMEM),
// leaving the LDS and vector-memory pipes idle.
// Decision (proven exact, rounds 5/6): q = fmaf(-0.45f, denom, inter) decides
// unless |q| <= 2^-20*denom (the 64x margin below which rounding could flip);
// rare uncertain lanes fall back to exact f64: inter > THETA*denom with
// THETA = 0.45f + 2^-26 (theta*(double)denom exact: 25+24 significand bits;
// tie rounds-to-even to T so strict '>' is bit-exact vs the reference).
__global__ __launch_bounds__(1024) void k_mask(const float* __restrict__ sel_box,
                                               unsigned long long* __restrict__ maskT) {
    int t = threadIdx.x;
    int lane = t & 63;
    int wv = t >> 6;
    const double THETA = (double)IOU_T + 0x1p-26;
    for (int job = blockIdx.x * 16 + wv; job < NB * 136; job += gridDim.x * 16) {
        int img = job / 136;
        int r   = job - img * 136;
        int jt = 0;
        while (((jt + 1) * (jt + 2)) / 2 <= r) ++jt;    // <=15 scalar iters
        int it = r - (jt * (jt + 1)) / 2;               // 0..jt
        img = __builtin_amdgcn_readfirstlane(img);
        jt  = __builtin_amdgcn_readfirstlane(jt);
        it  = __builtin_amdgcn_readfirstlane(it);
        const float4* bsrc = (const float4*)sel_box + (long)img * NSEL;
        float4 bi = bsrc[it * 64 + lane];   // per-lane row box, coalesced
        float  ai = (bi.z - bi.x) * (bi.w - bi.y);
        bool diag = (it == jt);
        const float4* bj_base = bsrc + jt * 64;   // wave-uniform -> s_load
        unsigned lo = 0u, hi = 0u;
#pragma unroll 16
        for (int j = 0; j < 64; ++j) {
            float4 bj = bj_base[j];               // scalar load (uniform)
            float aj = (bj.z - bj.x) * (bj.w - bj.y);
            float iw = fminf(bi.z, bj.z) - fmaxf(bi.x, bj.x);
            float ih = fminf(bi.w, bj.w) - fmaxf(bi.y, bj.y);
            iw = fmaxf(iw, 0.0f);
            ih = fmaxf(ih, 0.0f);
            float inter = iw * ih;
            float denom = ai + aj - inter + 1e-7f;   // f32, reference assoc
            float q = fmaf(-0.45f, denom, inter);    // single-rounded residual
            float marg = 0x1p-20f * denom;
            bool pred = q > marg;
            bool uncertain = !(fabsf(q) > marg);
            if (__any(uncertain))
                pred = ((double)inter > THETA * (double)denom);  // exact
            if (j < 32) lo |= pred ? (1u << j) : 0u;
            else        hi |= pred ? (1u << (j - 32)) : 0u;
        }
        unsigned long long word = ((unsigned long long)hi << 32) | (unsigned long long)lo;
        if (diag) word &= ~((2ull << lane) - 1ull);  // keep only j > i on diagonal
        maskT[((long)img * 16 + jt) * NSEL + it * 64 + lane] = word;
    }
}

// ---------------------------------------------------------------- sweep + output (blocked resolve)
__global__ __launch_bounds__(1024) void k_sweepout(const float* __restrict__ sel_score,
                                                   const float* __restrict__ sel_box,
                                                   const float* __restrict__ sel_cls,
                                                   const unsigned long long* __restrict__ maskT,
                                                   float* __restrict__ out) {
    __shared__ unsigned long long keepL[16];
    __shared__ unsigned int wsum[16];
    int img = blockIdx.x, t = threadIdx.x;
    int lane = t & 63, wid = t >> 6;
    const float* sc = sel_score + img * NSEL;

    // preload this wave's mask column (tiles above the diagonal never written/read)
    unsigned long long m[16];
    const unsigned long long* col = maskT + ((long)img * 16 + wid) * NSEL + lane;
#pragma unroll
    for (int tt = 0; tt < 16; ++tt)
        m[tt] = (tt <= wid) ? col[tt * 64] : 0ull;

    // zero the output while loads are in flight
    float* o = out + (long)img * NDET * 6;
    for (int e = t; e < NDET * 6; e += 1024) o[e] = 0.0f;

    unsigned long long kw = __ballot(sc[wid * 64 + lane] > CONF_T);

    for (int tt = 0; tt < 16; ++tt) {
        if (wid == tt) {
            unsigned mlo = (unsigned)(m[tt] & 0xFFFFFFFFull);
            unsigned mhi = (unsigned)(m[tt] >> 32);
#pragma unroll
            for (int i = 0; i < 64; ++i) {
                unsigned rlo = (unsigned)__builtin_amdgcn_readlane((int)mlo, i);
                unsigned rhi = (unsigned)__builtin_amdgcn_readlane((int)mhi, i);
                unsigned long long mrow =
                    ((unsigned long long)rhi << 32) | (unsigned long long)rlo;
                kw = ((kw >> i) & 1ull) ? (kw & ~mrow) : kw;
            }
            if (lane == 0) keepL[tt] = kw;
        }
        __syncthreads();
        if (wid > tt) {
            unsigned long long kwt = keepL[tt];
            unsigned long long v = ((kwt >> lane) & 1ull) ? m[tt] : 0ull;
#pragma unroll
            for (int s = 1; s < 64; s <<= 1)
                v |= __shfl_xor(v, s, 64);
            kw &= ~v;
        }
    }

    // output: rank kept rows, emit first 300
    bool kept = (kw >> lane) & 1ull;
    unsigned long long bal = __ballot(kept);
    int lrank = __popcll(bal & ((1ull << lane) - 1ull));
    if (lane == 0) wsum[wid] = (unsigned)__popcll(bal);
    __syncthreads();
    int off = 0;
    for (int ww = 0; ww < wid; ++ww) off += (int)wsum[ww];
    int rank = off + lrank;
    if (kept && rank < NDET) {
        float4 b = ((const float4*)sel_box)[img * NSEL + t];
        float s = sc[t];
        float c = sel_cls[img * NSEL + t];
        float* row = o + rank * 6;
        row[0] = b.x; row[1] = b.y; row[2] = b.z; row[3] = b.w;
        row[4] = s;   row[5] = c;
    }
}

// ---------------------------------------------------------------- launch
extern "C" void kernel_launch(void* const* d_in, const int* in_sizes, int n_in,
                              void* d_out, int out_size, void* d_ws, size_t ws_size,
                              hipStream_t stream) {
    const float* r0   = (const float*)d_in[0];
    const float* r1   = (const float*)d_in[1];
    const float* r2   = (const float*)d_in[2];
    const float* strd = (const float*)d_in[3];
    const float* ag   = (const float*)d_in[4];

    char* ws = (char*)d_ws;
    size_t off = 0;
    auto alloc = [&](size_t bytes) -> void* {
        void* p = ws + off;
        off += (bytes + 255) & ~(size_t)255;
        return p;
    };
    float* scores              = (float*)alloc((size_t)NB * NPRED * 4);
    float* sel_score           = (float*)alloc((size_t)NB * NSEL * 4);
    float* sel_box             = (float*)alloc((size_t)NB * NSEL * 16);
    float* sel_cls             = (float*)alloc((size_t)NB * NSEL * 4);
    unsigned long long* maskT  = (unsigned long long*)alloc((size_t)NB * 16 * NSEL * 8);
    float* out = (float*)d_out;

    k_score<<<6300, 256, 0, stream>>>(r0, r1, r2, scores);
    k_topk<<<NB, 1024, 0, stream>>>(scores, r0, r1, r2, strd, ag,
                                    sel_score, sel_box, sel_cls);
    k_mask<<<256, 1024, 0, stream>>>(sel_box, maskT);
    k_sweepout<<<NB, 1024, 0, stream>>>(sel_score, sel_box, sel_cls, maskT, out);
}

// Round 9
// 274.569 us; speedup vs baseline: 1.0809x; 1.0809x over previous
//
#include <hip/hip_runtime.h>

#define NB 64
#define NPRED 25200
#define NCAND 2048
#define NSEL 1024
#define NDET 300
#define NBINS 8192
#define CONF_T 0.25f
#define IOU_T 0.45f
#define BASE_BITS 0x3E800000u   // bits of 0.25f

__device__ __forceinline__ float sigmoidf_(float x) {
    return 1.0f / (1.0f + expf(-x));
}

// LDS slot swizzle: +1 float4 pad every 8 slots (conflict-free 80B-stride reads).
#define SLOT(x) ((x) + ((x) >> 3))

// Bitonic compare-exchange via wave shuffle (partner distance j <= 32 stays
// inside a wave64). Bit-identical to the LDS pass: element e keeps
// (lower==up) ? max : min, up = ((e&k)==0), lower = ((e&j)==0).
__device__ __forceinline__ unsigned long long cex_(unsigned long long x,
                                                   int e, int k, int j) {
    unsigned long long y = __shfl_xor(x, j, 64);
    bool up = ((e & k) == 0);
    bool lower = ((e & j) == 0);
    unsigned long long mn = (x < y) ? x : y;
    unsigned long long mx = (x < y) ? y : x;
    return (lower == up) ? mx : mn;
}

// ---------------------------------------------------------------- scores
__global__ __launch_bounds__(256) void k_score(const float* __restrict__ r0,
                                               const float* __restrict__ r1,
                                               const float* __restrict__ r2,
                                               float* __restrict__ scores) {
    __shared__ float4 sm[SLOT(1280)];   // 1440 slots = 23 KB
    int b = blockIdx.x;
    int t = threadIdx.x;
    const float* src;
    int rec, img, n;
    if (b < 4800) {
        src = r0; rec = b * 256 + t;
        img = rec / 19200; n = rec - img * 19200;
    } else if (b < 6000) {
        src = r1; rec = (b - 4800) * 256 + t;
        img = rec / 4800;  n = 19200 + rec - img * 4800;
    } else {
        src = r2; rec = (b - 6000) * 256 + t;
        img = rec / 1200;  n = 24000 + rec - img * 1200;
    }
    const float4* g = (const float4*)src + (long)(rec - t) * 5;  // block base
#pragma unroll
    for (int k = 0; k < 5; ++k) {
        int x = t + 256 * k;
        sm[SLOT(x)] = g[x];
    }
    __syncthreads();
    float4 v0 = sm[SLOT(5 * t + 1)];
    float4 v1 = sm[SLOT(5 * t + 2)];
    float4 v2 = sm[SLOT(5 * t + 3)];
    float4 v3 = sm[SLOT(5 * t + 4)];
    float obj = sigmoidf_(v0.x);
    float m = v0.y;
    m = fmaxf(m, v0.z); m = fmaxf(m, v0.w);
    m = fmaxf(m, v1.x); m = fmaxf(m, v1.y); m = fmaxf(m, v1.z); m = fmaxf(m, v1.w);
    m = fmaxf(m, v2.x); m = fmaxf(m, v2.y); m = fmaxf(m, v2.z); m = fmaxf(m, v2.w);
    m = fmaxf(m, v3.x); m = fmaxf(m, v3.y); m = fmaxf(m, v3.z); m = fmaxf(m, v3.w);
    float best = obj * sigmoidf_(m);
    float sc = (obj > CONF_T && best > CONF_T) ? best : 0.0f;
    scores[(long)img * NPRED + n] = sc;
}

// ---------------------------------------------------------------- top-k + decode (fused)
__global__ __launch_bounds__(1024) void k_topk(const float* __restrict__ scores,
                                               const float* __restrict__ r0,
                                               const float* __restrict__ r1,
                                               const float* __restrict__ r2,
                                               const float* __restrict__ strd,
                                               const float* __restrict__ ag,
                                               float* __restrict__ sel_score,
                                               float* __restrict__ sel_box,
                                               float* __restrict__ sel_cls) {
    __shared__ unsigned int hist[NBINS];
    __shared__ unsigned int bufA[1024];
    __shared__ unsigned int bufB[1024];
    __shared__ unsigned long long sbuf[NCAND];
    __shared__ unsigned int s_thr;
    __shared__ unsigned int s_cnt;
    int img = blockIdx.x;
    int t = threadIdx.x;
    for (int b = t; b < NBINS; b += 1024) hist[b] = 0;
    if (t == 0) { s_thr = 0; s_cnt = 0; }
    __syncthreads();
    const float* sc = scores + (long)img * NPRED;
    float v[25];
#pragma unroll
    for (int i = 0; i < 25; ++i) {
        int n = t + i * 1024;
        v[i] = (n < NPRED) ? sc[n] : 0.0f;
        if (v[i] > CONF_T) {
            unsigned bin = (__float_as_uint(v[i]) - BASE_BITS) >> 11;
            if (bin > NBINS - 1u) bin = NBINS - 1u;
            atomicAdd(&hist[bin], 1u);
        }
    }
    __syncthreads();
    unsigned h[8];
    unsigned cs = 0;
    for (int b = 0; b < 8; ++b) { h[b] = hist[t * 8 + b]; cs += h[b]; }
    bufA[t] = cs;
    __syncthreads();
    unsigned int* srcp = bufA;
    unsigned int* dstp = bufB;
    for (int ofs = 1; ofs < 1024; ofs <<= 1) {
        unsigned vv = srcp[t];
        if (t >= ofs) vv += srcp[t - ofs];
        dstp[t] = vv;
        __syncthreads();
        unsigned int* tmp = srcp; srcp = dstp; dstp = tmp;
    }
    unsigned total = srcp[1023];
    unsigned above = total - srcp[t];
    if (total >= NSEL) {
        unsigned c = above;
        for (int b = 7; b >= 0; --b) {
            unsigned ci = c + h[b];
            if (c < NSEL && ci >= NSEL) {
                s_thr = BASE_BITS + ((unsigned)(t * 8 + b) << 11);
            }
            c = ci;
        }
    }
    __syncthreads();
    unsigned thr = s_thr;
#pragma unroll
    for (int i = 0; i < 25; ++i) {
        int n = t + i * 1024;
        if (v[i] > CONF_T) {
            unsigned bits = __float_as_uint(v[i]);
            if (bits >= thr) {
                unsigned pos = atomicAdd(&s_cnt, 1u);
                if (pos < NCAND)
                    sbuf[pos] = ((unsigned long long)bits << 32) |
                                (unsigned long long)(0xFFFFFFFFu - (unsigned)n);
            }
        }
    }
    __syncthreads();
    for (unsigned pos = s_cnt + (unsigned)t; pos < NCAND; pos += 1024) sbuf[pos] = 0ull;
    __syncthreads();

    // ---- hybrid bitonic sort: j<=32 passes in-register via shfl_xor ----
    {
        unsigned long long a = sbuf[t];
        unsigned long long b = sbuf[t + 1024];
#pragma unroll
        for (int k = 2; k <= 64; k <<= 1) {
#pragma unroll
            for (int j = k >> 1; j >= 1; j >>= 1) {
                a = cex_(a, t, k, j);
                b = cex_(b, t + 1024, k, j);
            }
        }
        sbuf[t] = a; sbuf[t + 1024] = b;
    }
    __syncthreads();
    for (int k = 128; k <= NCAND; k <<= 1) {
        for (int j = k >> 1; j >= 64; j >>= 1) {
            for (int e = t; e < NCAND; e += 1024) {
                int p = e ^ j;
                if (p > e) {
                    unsigned long long a = sbuf[e], b = sbuf[p];
                    bool up = ((e & k) == 0);
                    if ((a < b) == up) { sbuf[e] = b; sbuf[p] = a; }
                }
            }
            __syncthreads();
        }
        unsigned long long a = sbuf[t];
        unsigned long long b = sbuf[t + 1024];
#pragma unroll
        for (int j = 32; j >= 1; j >>= 1) {
            a = cex_(a, t, k, j);
            b = cex_(b, t + 1024, k, j);
        }
        sbuf[t] = a; sbuf[t + 1024] = b;
        __syncthreads();
    }

    unsigned long long key = sbuf[t];
    float scv = __uint_as_float((unsigned)(key >> 32));
    int idx = (int)(0xFFFFFFFFu - (unsigned)(key & 0xFFFFFFFFull));
    sel_score[img * NSEL + t] = scv;

    // ---- fused decode of the selected prediction ----
    float4 bb = make_float4(0.f, 0.f, 0.f, 0.f);
    float cls = 0.0f;
    if (scv > CONF_T) {
        int n = idx;
        const float* src;
        int a, y, x, cells, sidx, nxl;
        if (n < 19200) {
            sidx = 0; src = r0; cells = 6400; nxl = 80;
            int l = n;            a = l / 6400; int r = l - a * 6400; y = r / 80; x = r - y * 80;
        } else if (n < 24000) {
            sidx = 1; src = r1; cells = 1600; nxl = 40;
            int l = n - 19200;    a = l / 1600; int r = l - a * 1600; y = r / 40; x = r - y * 40;
        } else {
            sidx = 2; src = r2; cells = 400; nxl = 20;
            int l = n - 24000;    a = l / 400;  int r = l - a * 400;  y = r / 20; x = r - y * 20;
        }
        long base = (((long)img * 3 + a) * cells + (long)y * nxl + x) * 20;
        const float4* p = (const float4*)(src + base);
        float4 v0 = p[0];
        float st = strd[sidx];
        float aw = ag[(sidx * 3 + a) * 2 + 0];
        float ah = ag[(sidx * 3 + a) * 2 + 1];
        float cx = (sigmoidf_(v0.x) * 2.0f - 0.5f + (float)x) * st;
        float cy = (sigmoidf_(v0.y) * 2.0f - 0.5f + (float)y) * st;
        float tw = sigmoidf_(v0.z) * 2.0f;
        float th = sigmoidf_(v0.w) * 2.0f;
        float w = tw * tw * aw;
        float hh = th * th * ah;
        bb.x = cx - w * 0.5f;
        bb.y = cy - hh * 0.5f;
        bb.z = cx + w * 0.5f;
        bb.w = cy + hh * 0.5f;
        float4 c0 = p[1], c1 = p[2], c2 = p[3], c3 = p[4];
        float vals[15] = { c0.y, c0.z, c0.w,
                           c1.x, c1.y, c1.z, c1.w,
                           c2.x, c2.y, c2.z, c2.w,
                           c3.x, c3.y, c3.z, c3.w };
        float bv = vals[0]; int bi = 0;
#pragma unroll
        for (int k = 1; k < 15; ++k) if (vals[k] > bv) { bv = vals[k]; bi = k; }
        cls = (float)bi;
    }
    ((float4*)sel_box)[img * NSEL + t] = bb;
    sel_cls[img * NSEL + t] = cls;
}

// ---------------------------------------------------------------- IoU mask (paired tiles, 2x ILP)
// maskT[img][jt][i]: bit b set <=> j=jt*64+b > i and IoU > 0.45.
// Each wave computes TWO i-tiles (it0=2q, it1=min(2q+1,jt)) against one j-tile
// jt, sharing the uniform bj stream. The two IoU chains are independent ->
// dual dependency chains interleave in the VALU pipeline, doubling useful
// issue per wave (the ~31us plateau was latency-bound at low occupancy).
// Pair layout: pairs for column jt start at S(jt) = floor((jt+1)^2/4);
// 72 pairs/image total. Odd columns pad with (jt,jt) duplicate -- double
// store of the same word to the same address, benign.
// Decision (proven exact, R2/R7): RN(inter/denom) > T <=> inter > THETA*denom,
// THETA = 0.45f + 2^-26 (half-ulp above); THETA*(double)denom exact in double
// (25+24 significand bits), tie rounds-to-even to T, strict '>' bit-exact.
__global__ __launch_bounds__(256) void k_mask(const float* __restrict__ sel_box,
                                              unsigned long long* __restrict__ maskT) {
    int t = threadIdx.x;
    int lane = t & 63;
    int wv = t >> 6;
    int job = blockIdx.x * 4 + wv;          // 0 .. 4607
    int img = job / 72;
    int p   = job - img * 72;
    int jt = 0;
    while (((jt + 2) * (jt + 2)) / 4 <= p) ++jt;        // <=15 scalar iters
    int q  = p - ((jt + 1) * (jt + 1)) / 4;             // pair index in column
    int it0 = 2 * q;
    int it1 = (2 * q + 1 < jt) ? (2 * q + 1) : jt;
    const float4* bsrc = (const float4*)sel_box + (long)img * NSEL;
    float4 bi0 = bsrc[it0 * 64 + lane];     // per-lane row boxes, coalesced
    float4 bi1 = bsrc[it1 * 64 + lane];
    float  ai0 = (bi0.z - bi0.x) * (bi0.w - bi0.y);
    float  ai1 = (bi1.z - bi1.x) * (bi1.w - bi1.y);
    const float4* bj_base = bsrc + jt * 64; // wave-uniform j stream
    const double THETA = (double)IOU_T + 0x1p-26;
    unsigned lo0 = 0u, hi0 = 0u, lo1 = 0u, hi1 = 0u;
#pragma unroll 8
    for (int j = 0; j < 64; ++j) {
        float4 bj = bj_base[j];             // uniform load, shared by chains
        float aj = (bj.z - bj.x) * (bj.w - bj.y);
        // chain 0
        float iw0 = fminf(bi0.z, bj.z) - fmaxf(bi0.x, bj.x);
        float ih0 = fminf(bi0.w, bj.w) - fmaxf(bi0.y, bj.y);
        iw0 = fmaxf(iw0, 0.0f); ih0 = fmaxf(ih0, 0.0f);
        float in0 = iw0 * ih0;
        float dn0 = ai0 + aj - in0 + 1e-7f;
        bool p0 = ((double)in0 > THETA * (double)dn0);
        // chain 1 (independent)
        float iw1 = fminf(bi1.z, bj.z) - fmaxf(bi1.x, bj.x);
        float ih1 = fminf(bi1.w, bj.w) - fmaxf(bi1.y, bj.y);
        iw1 = fmaxf(iw1, 0.0f); ih1 = fmaxf(ih1, 0.0f);
        float in1 = iw1 * ih1;
        float dn1 = ai1 + aj - in1 + 1e-7f;
        bool p1 = ((double)in1 > THETA * (double)dn1);
        if (j < 32) { lo0 |= p0 ? (1u << j) : 0u;        lo1 |= p1 ? (1u << j) : 0u; }
        else        { hi0 |= p0 ? (1u << (j - 32)) : 0u; hi1 |= p1 ? (1u << (j - 32)) : 0u; }
    }
    unsigned long long w0 = ((unsigned long long)hi0 << 32) | (unsigned long long)lo0;
    unsigned long long w1 = ((unsigned long long)hi1 << 32) | (unsigned long long)lo1;
    if (it0 == jt) w0 &= ~((2ull << lane) - 1ull);  // diagonal: keep only j > i
    if (it1 == jt) w1 &= ~((2ull << lane) - 1ull);
    unsigned long long* base = maskT + ((long)img * 16 + jt) * NSEL;
    base[it0 * 64 + lane] = w0;
    base[it1 * 64 + lane] = w1;
}

// ---------------------------------------------------------------- sweep + output (blocked resolve)
__global__ __launch_bounds__(1024) void k_sweepout(const float* __restrict__ sel_score,
                                                   const float* __restrict__ sel_box,
                                                   const float* __restrict__ sel_cls,
                                                   const unsigned long long* __restrict__ maskT,
                                                   float* __restrict__ out) {
    __shared__ unsigned long long keepL[16];
    __shared__ unsigned int wsum[16];
    int img = blockIdx.x, t = threadIdx.x;
    int lane = t & 63, wid = t >> 6;
    const float* sc = sel_score + img * NSEL;

    // preload this wave's mask column (tiles above the diagonal never written/read)
    unsigned long long m[16];
    const unsigned long long* col = maskT + ((long)img * 16 + wid) * NSEL + lane;
#pragma unroll
    for (int tt = 0; tt < 16; ++tt)
        m[tt] = (tt <= wid) ? col[tt * 64] : 0ull;

    // zero the output while loads are in flight
    float* o = out + (long)img * NDET * 6;
    for (int e = t; e < NDET * 6; e += 1024) o[e] = 0.0f;

    unsigned long long kw = __ballot(sc[wid * 64 + lane] > CONF_T);

    for (int tt = 0; tt < 16; ++tt) {
        if (wid == tt) {
            unsigned mlo = (unsigned)(m[tt] & 0xFFFFFFFFull);
            unsigned mhi = (unsigned)(m[tt] >> 32);
#pragma unroll
            for (int i = 0; i < 64; ++i) {
                unsigned rlo = (unsigned)__builtin_amdgcn_readlane((int)mlo, i);
                unsigned rhi = (unsigned)__builtin_amdgcn_readlane((int)mhi, i);
                unsigned long long mrow =
                    ((unsigned long long)rhi << 32) | (unsigned long long)rlo;
                kw = ((kw >> i) & 1ull) ? (kw & ~mrow) : kw;
            }
            if (lane == 0) keepL[tt] = kw;
        }
        __syncthreads();
        if (wid > tt) {
            unsigned long long kwt = keepL[tt];
            unsigned long long v = ((kwt >> lane) & 1ull) ? m[tt] : 0ull;
#pragma unroll
            for (int s = 1; s < 64; s <<= 1)
                v |= __shfl_xor(v, s, 64);
            kw &= ~v;
        }
    }

    // output: rank kept rows, emit first 300
    bool kept = (kw >> lane) & 1ull;
    unsigned long long bal = __ballot(kept);
    int lrank = __popcll(bal & ((1ull << lane) - 1ull));
    if (lane == 0) wsum[wid] = (unsigned)__popcll(bal);
    __syncthreads();
    int off = 0;
    for (int ww = 0; ww < wid; ++ww) off += (int)wsum[ww];
    int rank = off + lrank;
    if (kept && rank < NDET) {
        float4 b = ((const float4*)sel_box)[img * NSEL + t];
        float s = sc[t];
        float c = sel_cls[img * NSEL + t];
        float* row = o + rank * 6;
        row[0] = b.x; row[1] = b.y; row[2] = b.z; row[3] = b.w;
        row[4] = s;   row[5] = c;
    }
}

// ---------------------------------------------------------------- launch
extern "C" void kernel_launch(void* const* d_in, const int* in_sizes, int n_in,
                              void* d_out, int out_size, void* d_ws, size_t ws_size,
                              hipStream_t stream) {
    const float* r0   = (const float*)d_in[0];
    const float* r1   = (const float*)d_in[1];
    const float* r2   = (const float*)d_in[2];
    const float* strd = (const float*)d_in[3];
    const float* ag   = (const float*)d_in[4];

    char* ws = (char*)d_ws;
    size_t off = 0;
    auto alloc = [&](size_t bytes) -> void* {
        void* p = ws + off;
        off += (bytes + 255) & ~(size_t)255;
        return p;
    };
    float* scores              = (float*)alloc((size_t)NB * NPRED * 4);
    float* sel_score           = (float*)alloc((size_t)NB * NSEL * 4);
    float* sel_box             = (float*)alloc((size_t)NB * NSEL * 16);
    float* sel_cls             = (float*)alloc((size_t)NB * NSEL * 4);
    unsigned long long* maskT  = (unsigned long long*)alloc((size_t)NB * 16 * NSEL * 8);
    float* out = (float*)d_out;

    k_score<<<6300, 256, 0, stream>>>(r0, r1, r2, scores);
    k_topk<<<NB, 1024, 0, stream>>>(scores, r0, r1, r2, strd, ag,
                                    sel_score, sel_box, sel_cls);
    k_mask<<<1152, 256, 0, stream>>>(sel_box, maskT);
    k_sweepout<<<NB, 1024, 0, stream>>>(sel_score, sel_box, sel_cls, maskT, out);
}

// Round 10
// 269.670 us; speedup vs baseline: 1.1006x; 1.0182x over previous
//
#include <hip/hip_runtime.h>

#define NB 64
#define NPRED 25200
#define NCAND 2048
#define NSEL 1024
#define NDET 300
#define NBINS 8192
#define CONF_T 0.25f
#define IOU_T 0.45f
#define BASE_BITS 0x3E800000u   // bits of 0.25f

__device__ __forceinline__ float sigmoidf_(float x) {
    return 1.0f / (1.0f + expf(-x));
}

// LDS slot swizzle: +1 float4 pad every 8 slots (conflict-free 80B-stride reads).
#define SLOT(x) ((x) + ((x) >> 3))

// Bitonic compare-exchange via wave shuffle (partner distance j <= 32 stays
// inside a wave64). Bit-identical to the LDS pass: element e keeps
// (lower==up) ? max : min, up = ((e&k)==0), lower = ((e&j)==0).
__device__ __forceinline__ unsigned long long cex_(unsigned long long x,
                                                   int e, int k, int j) {
    unsigned long long y = __shfl_xor(x, j, 64);
    bool up = ((e & k) == 0);
    bool lower = ((e & j) == 0);
    unsigned long long mn = (x < y) ? x : y;
    unsigned long long mx = (x < y) ? y : x;
    return (lower == up) ? mx : mn;
}

// ---------------------------------------------------------------- scores
__global__ __launch_bounds__(256) void k_score(const float* __restrict__ r0,
                                               const float* __restrict__ r1,
                                               const float* __restrict__ r2,
                                               float* __restrict__ scores) {
    __shared__ float4 sm[SLOT(1280)];   // 1440 slots = 23 KB
    int b = blockIdx.x;
    int t = threadIdx.x;
    const float* src;
    int rec, img, n;
    if (b < 4800) {
        src = r0; rec = b * 256 + t;
        img = rec / 19200; n = rec - img * 19200;
    } else if (b < 6000) {
        src = r1; rec = (b - 4800) * 256 + t;
        img = rec / 4800;  n = 19200 + rec - img * 4800;
    } else {
        src = r2; rec = (b - 6000) * 256 + t;
        img = rec / 1200;  n = 24000 + rec - img * 1200;
    }
    const float4* g = (const float4*)src + (long)(rec - t) * 5;  // block base
#pragma unroll
    for (int k = 0; k < 5; ++k) {
        int x = t + 256 * k;
        sm[SLOT(x)] = g[x];
    }
    __syncthreads();
    float4 v0 = sm[SLOT(5 * t + 1)];
    float4 v1 = sm[SLOT(5 * t + 2)];
    float4 v2 = sm[SLOT(5 * t + 3)];
    float4 v3 = sm[SLOT(5 * t + 4)];
    float obj = sigmoidf_(v0.x);
    float m = v0.y;
    m = fmaxf(m, v0.z); m = fmaxf(m, v0.w);
    m = fmaxf(m, v1.x); m = fmaxf(m, v1.y); m = fmaxf(m, v1.z); m = fmaxf(m, v1.w);
    m = fmaxf(m, v2.x); m = fmaxf(m, v2.y); m = fmaxf(m, v2.z); m = fmaxf(m, v2.w);
    m = fmaxf(m, v3.x); m = fmaxf(m, v3.y); m = fmaxf(m, v3.z); m = fmaxf(m, v3.w);
    float best = obj * sigmoidf_(m);
    float sc = (obj > CONF_T && best > CONF_T) ? best : 0.0f;
    scores[(long)img * NPRED + n] = sc;
}

// ---------------------------------------------------------------- top-k + decode (fused)
__global__ __launch_bounds__(1024) void k_topk(const float* __restrict__ scores,
                                               const float* __restrict__ r0,
                                               const float* __restrict__ r1,
                                               const float* __restrict__ r2,
                                               const float* __restrict__ strd,
                                               const float* __restrict__ ag,
                                               float* __restrict__ sel_score,
                                               float* __restrict__ sel_box,
                                               float* __restrict__ sel_cls) {
    __shared__ unsigned int hist[NBINS];
    __shared__ unsigned int bufA[1024];
    __shared__ unsigned int bufB[1024];
    __shared__ unsigned long long sbuf[NCAND];
    __shared__ unsigned int s_thr;
    __shared__ unsigned int s_cnt;
    int img = blockIdx.x;
    int t = threadIdx.x;
    for (int b = t; b < NBINS; b += 1024) hist[b] = 0;
    if (t == 0) { s_thr = 0; s_cnt = 0; }
    __syncthreads();
    const float* sc = scores + (long)img * NPRED;
    float v[25];
#pragma unroll
    for (int i = 0; i < 25; ++i) {
        int n = t + i * 1024;
        v[i] = (n < NPRED) ? sc[n] : 0.0f;
        if (v[i] > CONF_T) {
            unsigned bin = (__float_as_uint(v[i]) - BASE_BITS) >> 11;
            if (bin > NBINS - 1u) bin = NBINS - 1u;
            atomicAdd(&hist[bin], 1u);
        }
    }
    __syncthreads();
    unsigned h[8];
    unsigned cs = 0;
    for (int b = 0; b < 8; ++b) { h[b] = hist[t * 8 + b]; cs += h[b]; }
    bufA[t] = cs;
    __syncthreads();
    unsigned int* srcp = bufA;
    unsigned int* dstp = bufB;
    for (int ofs = 1; ofs < 1024; ofs <<= 1) {
        unsigned vv = srcp[t];
        if (t >= ofs) vv += srcp[t - ofs];
        dstp[t] = vv;
        __syncthreads();
        unsigned int* tmp = srcp; srcp = dstp; dstp = tmp;
    }
    unsigned total = srcp[1023];
    unsigned above = total - srcp[t];
    if (total >= NSEL) {
        unsigned c = above;
        for (int b = 7; b >= 0; --b) {
            unsigned ci = c + h[b];
            if (c < NSEL && ci >= NSEL) {
                s_thr = BASE_BITS + ((unsigned)(t * 8 + b) << 11);
            }
            c = ci;
        }
    }
    __syncthreads();
    unsigned thr = s_thr;
#pragma unroll
    for (int i = 0; i < 25; ++i) {
        int n = t + i * 1024;
        if (v[i] > CONF_T) {
            unsigned bits = __float_as_uint(v[i]);
            if (bits >= thr) {
                unsigned pos = atomicAdd(&s_cnt, 1u);
                if (pos < NCAND)
                    sbuf[pos] = ((unsigned long long)bits << 32) |
                                (unsigned long long)(0xFFFFFFFFu - (unsigned)n);
            }
        }
    }
    __syncthreads();
    for (unsigned pos = s_cnt + (unsigned)t; pos < NCAND; pos += 1024) sbuf[pos] = 0ull;
    __syncthreads();

    // ---- hybrid bitonic sort: j<=32 passes in-register via shfl_xor ----
    {
        unsigned long long a = sbuf[t];
        unsigned long long b = sbuf[t + 1024];
#pragma unroll
        for (int k = 2; k <= 64; k <<= 1) {
#pragma unroll
            for (int j = k >> 1; j >= 1; j >>= 1) {
                a = cex_(a, t, k, j);
                b = cex_(b, t + 1024, k, j);
            }
        }
        sbuf[t] = a; sbuf[t + 1024] = b;
    }
    __syncthreads();
    for (int k = 128; k <= NCAND; k <<= 1) {
        for (int j = k >> 1; j >= 64; j >>= 1) {
            for (int e = t; e < NCAND; e += 1024) {
                int p = e ^ j;
                if (p > e) {
                    unsigned long long a = sbuf[e], b = sbuf[p];
                    bool up = ((e & k) == 0);
                    if ((a < b) == up) { sbuf[e] = b; sbuf[p] = a; }
                }
            }
            __syncthreads();
        }
        unsigned long long a = sbuf[t];
        unsigned long long b = sbuf[t + 1024];
#pragma unroll
        for (int j = 32; j >= 1; j >>= 1) {
            a = cex_(a, t, k, j);
            b = cex_(b, t + 1024, k, j);
        }
        sbuf[t] = a; sbuf[t + 1024] = b;
        __syncthreads();
    }

    unsigned long long key = sbuf[t];
    float scv = __uint_as_float((unsigned)(key >> 32));
    int idx = (int)(0xFFFFFFFFu - (unsigned)(key & 0xFFFFFFFFull));
    sel_score[img * NSEL + t] = scv;

    // ---- fused decode of the selected prediction ----
    float4 bb = make_float4(0.f, 0.f, 0.f, 0.f);
    float cls = 0.0f;
    if (scv > CONF_T) {
        int n = idx;
        const float* src;
        int a, y, x, cells, sidx, nxl;
        if (n < 19200) {
            sidx = 0; src = r0; cells = 6400; nxl = 80;
            int l = n;            a = l / 6400; int r = l - a * 6400; y = r / 80; x = r - y * 80;
        } else if (n < 24000) {
            sidx = 1; src = r1; cells = 1600; nxl = 40;
            int l = n - 19200;    a = l / 1600; int r = l - a * 1600; y = r / 40; x = r - y * 40;
        } else {
            sidx = 2; src = r2; cells = 400; nxl = 20;
            int l = n - 24000;    a = l / 400;  int r = l - a * 400;  y = r / 20; x = r - y * 20;
        }
        long base = (((long)img * 3 + a) * cells + (long)y * nxl + x) * 20;
        const float4* p = (const float4*)(src + base);
        float4 v0 = p[0];
        float st = strd[sidx];
        float aw = ag[(sidx * 3 + a) * 2 + 0];
        float ah = ag[(sidx * 3 + a) * 2 + 1];
        float cx = (sigmoidf_(v0.x) * 2.0f - 0.5f + (float)x) * st;
        float cy = (sigmoidf_(v0.y) * 2.0f - 0.5f + (float)y) * st;
        float tw = sigmoidf_(v0.z) * 2.0f;
        float th = sigmoidf_(v0.w) * 2.0f;
        float w = tw * tw * aw;
        float hh = th * th * ah;
        bb.x = cx - w * 0.5f;
        bb.y = cy - hh * 0.5f;
        bb.z = cx + w * 0.5f;
        bb.w = cy + hh * 0.5f;
        float4 c0 = p[1], c1 = p[2], c2 = p[3], c3 = p[4];
        float vals[15] = { c0.y, c0.z, c0.w,
                           c1.x, c1.y, c1.z, c1.w,
                           c2.x, c2.y, c2.z, c2.w,
                           c3.x, c3.y, c3.z, c3.w };
        float bv = vals[0]; int bi = 0;
#pragma unroll
        for (int k = 1; k < 15; ++k) if (vals[k] > bv) { bv = vals[k]; bi = k; }
        cls = (float)bi;
    }
    ((float4*)sel_box)[img * NSEL + t] = bb;
    sel_cls[img * NSEL + t] = cls;
}

// ---------------------------------------------------------------- IoU mask (tiled)
// maskT[img][jt][i]: bit b set <=> j=jt*64+b > i and IoU > 0.45.
// LDS-broadcast inner loop (uniform-address ds_read = free broadcast).
// Division-free exact compare: RN(inter/denom) > T  <=>  inter > theta*denom
// with theta = T + 2^-26 (half-ulp above 0.45f); theta*(double)denom is EXACT
// in double (25+24 significand bits), tie at theta rounds-to-even to T, so
// strict '>' reproduces the reference bit-for-bit.
// Grid covers only upper-tri tile groups: 40 blocks/image. (Best-measured
// configuration: R7, 272.7 us total.)
__global__ __launch_bounds__(256) void k_mask(const float* __restrict__ sel_box,
                                              unsigned long long* __restrict__ maskT) {
    __shared__ float4 boxi[64];
    __shared__ float  areai[64];
    int bid = blockIdx.x;
    int img = bid / 40;
    int r   = bid - img * 40;
    int it, g;
    if (r < 16)      { it = r >> 2;                 g = r & 3; }
    else if (r < 28) { int k = r - 16; int q = k / 3; it = 4 + q;        g = 1 + (k - q * 3); }
    else if (r < 36) { int k = r - 28; it = 8 + (k >> 1); g = 2 + (k & 1); }
    else             { it = 12 + (r - 36);          g = 3; }
    int t = threadIdx.x;
    int wv = t >> 6;            // wave 0..3
    int lane = t & 63;
    const float4* bsrc = (const float4*)sel_box + (long)img * NSEL;
    if (t < 64) {
        float4 b = bsrc[it * 64 + t];
        boxi[t] = b;
        areai[t] = (b.z - b.x) * (b.w - b.y);
    }
    __syncthreads();
    int jt = g * 4 + wv;        // tile of j
    if (jt < it) return;        // wave-uniform exit
    float4 bj = bsrc[jt * 64 + lane];
    float aj = (bj.z - bj.x) * (bj.w - bj.y);
    bool diag = (jt == it);
    const double THETA = (double)IOU_T + 0x1p-26;   // exact half-ulp above 0.45f
    unsigned long long myword = 0;
#pragma unroll 16
    for (int i = 0; i < 64; ++i) {
        float4 bi = boxi[i];
        float ai = areai[i];
        float iw = fminf(bi.z, bj.z) - fmaxf(bi.x, bj.x);
        float ih = fminf(bi.w, bj.w) - fmaxf(bi.y, bj.y);
        iw = fmaxf(iw, 0.0f);
        ih = fmaxf(ih, 0.0f);
        float inter = iw * ih;
        float denom = ai + aj - inter + 1e-7f;      // f32, same assoc as reference
        bool pred = ((double)inter > THETA * (double)denom);
        pred = pred && (!diag || lane > i);
        unsigned long long bal = __ballot(pred);
        if (lane == i) myword = bal;
    }
    maskT[((long)img * 16 + jt) * NSEL + it * 64 + lane] = myword;
}

// ---------------------------------------------------------------- sweep + output (blocked resolve)
__global__ __launch_bounds__(1024) void k_sweepout(const float* __restrict__ sel_score,
                                                   const float* __restrict__ sel_box,
                                                   const float* __restrict__ sel_cls,
                                                   const unsigned long long* __restrict__ maskT,
                                                   float* __restrict__ out) {
    __shared__ unsigned long long keepL[16];
    __shared__ unsigned int wsum[16];
    int img = blockIdx.x, t = threadIdx.x;
    int lane = t & 63, wid = t >> 6;
    const float* sc = sel_score + img * NSEL;

    // preload this wave's mask column (tiles above the diagonal never written/read)
    unsigned long long m[16];
    const unsigned long long* col = maskT + ((long)img * 16 + wid) * NSEL + lane;
#pragma unroll
    for (int tt = 0; tt < 16; ++tt)
        m[tt] = (tt <= wid) ? col[tt * 64] : 0ull;

    // zero the output while loads are in flight
    float* o = out + (long)img * NDET * 6;
    for (int e = t; e < NDET * 6; e += 1024) o[e] = 0.0f;

    unsigned long long kw = __ballot(sc[wid * 64 + lane] > CONF_T);

    for (int tt = 0; tt < 16; ++tt) {
        if (wid == tt) {
            unsigned mlo = (unsigned)(m[tt] & 0xFFFFFFFFull);
            unsigned mhi = (unsigned)(m[tt] >> 32);
#pragma unroll
            for (int i = 0; i < 64; ++i) {
                unsigned rlo = (unsigned)__builtin_amdgcn_readlane((int)mlo, i);
                unsigned rhi = (unsigned)__builtin_amdgcn_readlane((int)mhi, i);
                unsigned long long mrow =
                    ((unsigned long long)rhi << 32) | (unsigned long long)rlo;
                kw = ((kw >> i) & 1ull) ? (kw & ~mrow) : kw;
            }
            if (lane == 0) keepL[tt] = kw;
        }
        __syncthreads();
        if (wid > tt) {
            unsigned long long kwt = keepL[tt];
            unsigned long long v = ((kwt >> lane) & 1ull) ? m[tt] : 0ull;
#pragma unroll
            for (int s = 1; s < 64; s <<= 1)
                v |= __shfl_xor(v, s, 64);
            kw &= ~v;
        }
    }

    // output: rank kept rows, emit first 300
    bool kept = (kw >> lane) & 1ull;
    unsigned long long bal = __ballot(kept);
    int lrank = __popcll(bal & ((1ull << lane) - 1ull));
    if (lane == 0) wsum[wid] = (unsigned)__popcll(bal);
    __syncthreads();
    int off = 0;
    for (int ww = 0; ww < wid; ++ww) off += (int)wsum[ww];
    int rank = off + lrank;
    if (kept && rank < NDET) {
        float4 b = ((const float4*)sel_box)[img * NSEL + t];
        float s = sc[t];
        float c = sel_cls[img * NSEL + t];
        float* row = o + rank * 6;
        row[0] = b.x; row[1] = b.y; row[2] = b.z; row[3] = b.w;
        row[4] = s;   row[5] = c;
    }
}

// ---------------------------------------------------------------- launch
extern "C" void kernel_launch(void* const* d_in, const int* in_sizes, int n_in,
                              void* d_out, int out_size, void* d_ws, size_t ws_size,
                              hipStream_t stream) {
    const float* r0   = (const float*)d_in[0];
    const float* r1   = (const float*)d_in[1];
    const float* r2   = (const float*)d_in[2];
    const float* strd = (const float*)d_in[3];
    const float* ag   = (const float*)d_in[4];

    char* ws = (char*)d_ws;
    size_t off = 0;
    auto alloc = [&](size_t bytes) -> void* {
        void* p = ws + off;
        off += (bytes + 255) & ~(size_t)255;
        return p;
    };
    float* scores              = (float*)alloc((size_t)NB * NPRED * 4);
    float* sel_score           = (float*)alloc((size_t)NB * NSEL * 4);
    float* sel_box             = (float*)alloc((size_t)NB * NSEL * 16);
    float* sel_cls             = (float*)alloc((size_t)NB * NSEL * 4);
    unsigned long long* maskT  = (unsigned long long*)alloc((size_t)NB * 16 * NSEL * 8);
    float* out = (float*)d_out;

    k_score<<<6300, 256, 0, stream>>>(r0, r1, r2, scores);
    k_topk<<<NB, 1024, 0, stream>>>(scores, r0, r1, r2, strd, ag,
                                    sel_score, sel_box, sel_cls);
    k_mask<<<NB * 40, 256, 0, stream>>>(sel_box, maskT);
    k_sweepout<<<NB, 1024, 0, stream>>>(sel_score, sel_box, sel_cls, maskT, out);
}